// Round 12
// baseline (418.338 us; speedup 1.0000x reference)
//
#include <hip/hip_runtime.h>
#include <hip/hip_bf16.h>

// GRU policy: B=2048, T=512, V=4, E=64, H=128.
// R11: regime change — 4 waves/block (256 thr), 1 wave per SIMD.
// Each wave owns 6 MFMA chains (3 gates x 2 col-halves, 24 MFMA/step, 8
// h-values/lane). With one wave per SIMD, program order = machine order, so
// sched_barrier(0) fences pin the interleave: [r+z chains 16 MFMA] ->
// [r/z trans + next-gi LDS, hidden under matrix drain] -> [n chains 8 MFMA]
// -> [short tail]. Same per-SIMD issue totals as R9/R10 but trans/VALU now
// overlap the matrix pipe by construction (the 2-wave barrier-lockstep
// regime provably serialized them: R4/R7/R8/R10 ledger).
// 128 blocks (structural: B/16 indep. groups), 1 barrier/step.

#define B_  2048
#define T_  512
#define V_  4
#define E_  64
#define H_  128
#define G3  384
#define SH  136            // h row stride (bf16 elems)

#define LOG2E 1.4426950408889634f

typedef __attribute__((ext_vector_type(8))) short  short8;   // 8 bf16
typedef __attribute__((ext_vector_type(4))) float  float4v;
typedef unsigned long long ull;

__device__ __forceinline__ short bf16s(float f) {            // RNE scalar (setup only)
  union { float ff; unsigned int u; } c; c.ff = f;
  return (short)((c.u + 0x7fffu + ((c.u >> 16) & 1u)) >> 16);
}

// table[v][g] = scale_g * (b_ih[g] + sum_e W_ih[g,e]*emb[v,e] (+ b_hh[g] for g<2H))
// scale_g = -log2e for r,z rows; +2*log2e for n rows (b_hh_n NOT folded).
__global__ void gi_table_kernel(const float* __restrict__ emb,
                                const float* __restrict__ W_ih,
                                const float* __restrict__ b_ih,
                                const float* __restrict__ b_hh,
                                float* __restrict__ table) {
  int gid = blockIdx.x * blockDim.x + threadIdx.x;
  if (gid >= V_ * G3) return;
  int v = gid / G3;
  int g = gid - v * G3;
  float acc = b_ih[g];
  if (g < 2 * H_) acc += b_hh[g];
  const float* wr = W_ih + g * E_;
  const float* er = emb + v * E_;
#pragma unroll 8
  for (int e = 0; e < E_; ++e) acc += wr[e] * er[e];
  table[gid] = acc * ((g < 2 * H_) ? -LOG2E : 2.f * LOG2E);
}

#define MFMA16(A, B, C) __builtin_amdgcn_mfma_f32_16x16x32_bf16((A), (B), (C), 0, 0, 0)
#define SFENCE() __builtin_amdgcn_sched_barrier(0)

__global__ __launch_bounds__(256, 1) void gru_kernel(
    const int* __restrict__ x, const float* __restrict__ W_hh,
    const float* __restrict__ b_hh, const float* __restrict__ W_fc,
    const float* __restrict__ b_fc, const float* __restrict__ table,
    float* __restrict__ out) {
  __shared__ __align__(16) short hbuf[2][16 * SH];          // bf16 h, double-buffered
  __shared__ __align__(16) unsigned char xs[(T_ + 2) * 16]; // tokens [t][row], 2 pad rows
  __shared__ __align__(16) float tabS[V_ * G3];             // gi table (pre-scaled)
  __shared__ __align__(16) float hf[16 * H_];               // epilogue fp32 h

  const int tid  = threadIdx.x;
  const int w    = tid >> 6;        // wave 0..3
  const int lane = tid & 63;
  const int m    = lane & 15;       // batch row (B/C col) and A gate-row
  const int q    = lane >> 4;       // quad
  const int g0   = blockIdx.x * 16;

  // ---- stage x -> xs[t][r] bytes; zero the 2 pad rows ----
  for (int i = tid; i < 16 * T_; i += 256) {
    int r = i >> 9;                 // 0..15
    int t = i & (T_ - 1);
    xs[t * 16 + r] = (unsigned char)(x[(g0 + r) * T_ + t] & 3);
  }
  if (tid < 32) xs[T_ * 16 + tid] = 0;
  // ---- stage gi table to LDS ----
  for (int i = tid; i < V_ * G3; i += 256) tabS[i] = table[i];
  // ---- h0 = 0 ----
  for (int i = tid; i < 16 * SH; i += 256) hbuf[0][i] = 0;

  // ---- persistent A-fragments: W_hh tiles (pre-scaled), 6 chains ----
  // chain c = s*2 + half covers gate rows s*128 + half*64 + w*16 + m.
  short8 wA[6][4];
#pragma unroll
  for (int s = 0; s < 3; ++s) {
    const float sc = (s < 2) ? -LOG2E : 2.f * LOG2E;
#pragma unroll
    for (int hh = 0; hh < 2; ++hh) {
      const float* wrow = W_hh + (s * H_ + hh * 64 + w * 16 + m) * H_;
#pragma unroll
      for (int ks = 0; ks < 4; ++ks) {
        const float* p = wrow + ks * 32 + q * 8;
        short8 f;
#pragma unroll
        for (int jj = 0; jj < 8; ++jj) f[jj] = bf16s(p[jj] * sc);
        wA[s * 2 + hh][ks] = f;
      }
    }
  }

  const int c0 = w * 16 + q * 4;    // this lane's h-col base (half 0); half 1 = +64
  float4v bhnC0, bhnC1;             // n-chain C-inits: b_hh_n * 2log2e
  {
    const float* p = b_hh + 2 * H_ + c0;
#pragma unroll
    for (int i = 0; i < 4; ++i) { bhnC0[i] = p[i] * 2.f * LOG2E; bhnC1[i] = p[64 + i] * 2.f * LOG2E; }
  }
  float h_old[8] = {0.f, 0.f, 0.f, 0.f, 0.f, 0.f, 0.f, 0.f};

  __syncthreads();

  // ---- prologue: gi(0) into set A (6 vecs, stride-64); token of t=1 ----
  float4v gA[6], gB[6];
  int vb;
  {
    int v0 = xs[m] & 3;
    const float* tb = &tabS[v0 * G3 + c0];
#pragma unroll
    for (int k = 0; k < 6; ++k) gA[k] = *(const float4v*)(tb + 64 * k);
    vb = xs[16 + m];
  }
  // gi index map: k=0,1 -> r half0/1; k=2,3 -> z; k=4,5 -> n.

  auto step = [&](int FROM, int TO, int t, float4v* gu, float4v* gl) {
    // h fragments — gate this step's MFMAs (B operand, shared by all 6 chains)
    const short* rbp = &hbuf[FROM][m * SH + q * 8];
    short8 h0 = *(const short8*)(rbp);
    short8 h1 = *(const short8*)(rbp + 32);
    short8 h2 = *(const short8*)(rbp + 64);
    short8 h3 = *(const short8*)(rbp + 96);

    // ---- group 1: r and z chains, both halves (16 MFMA, round-robin) ----
    float4v aR0 = MFMA16(wA[0][0], h0, gu[0]);
    float4v aR1 = MFMA16(wA[1][0], h0, gu[1]);
    float4v aZ0 = MFMA16(wA[2][0], h0, gu[2]);
    float4v aZ1 = MFMA16(wA[3][0], h0, gu[3]);
    aR0 = MFMA16(wA[0][1], h1, aR0);
    aR1 = MFMA16(wA[1][1], h1, aR1);
    aZ0 = MFMA16(wA[2][1], h1, aZ0);
    aZ1 = MFMA16(wA[3][1], h1, aZ1);
    aR0 = MFMA16(wA[0][2], h2, aR0);
    aR1 = MFMA16(wA[1][2], h2, aR1);
    aZ0 = MFMA16(wA[2][2], h2, aZ0);
    aZ1 = MFMA16(wA[3][2], h2, aZ1);
    aR0 = MFMA16(wA[0][3], h3, aR0);
    aR1 = MFMA16(wA[1][3], h3, aR1);
    aZ0 = MFMA16(wA[2][3], h3, aZ0);
    aZ1 = MFMA16(wA[3][3], h3, aZ1);
    SFENCE();
    // ---- group 2: next-gi LDS + r/z trans (hidden under the matrix drain) ----
    int vb2 = xs[(t + 2) * 16 + m];
    const float* tbn = &tabS[(vb & 3) * G3 + c0];
    gl[0] = *(const float4v*)(tbn);
    gl[1] = *(const float4v*)(tbn + 64);
    gl[2] = *(const float4v*)(tbn + 128);
    gl[3] = *(const float4v*)(tbn + 192);
    gl[4] = *(const float4v*)(tbn + 256);
    gl[5] = *(const float4v*)(tbn + 320);
    vb = vb2;
    float r[8], Ez[8];
#pragma unroll
    for (int i = 0; i < 4; ++i) {
      r[i]     = __builtin_amdgcn_rcpf(1.f + __builtin_amdgcn_exp2f(aR0[i]));
      r[4 + i] = __builtin_amdgcn_rcpf(1.f + __builtin_amdgcn_exp2f(aR1[i]));
      Ez[i]     = __builtin_amdgcn_exp2f(aZ0[i]);
      Ez[4 + i] = __builtin_amdgcn_exp2f(aZ1[i]);
    }
    SFENCE();
    // ---- group 3: n chains, both halves (8 MFMA) ----
    float4v aN0 = MFMA16(wA[4][0], h0, bhnC0);
    float4v aN1 = MFMA16(wA[5][0], h0, bhnC1);
    aN0 = MFMA16(wA[4][1], h1, aN0);
    aN1 = MFMA16(wA[5][1], h1, aN1);
    aN0 = MFMA16(wA[4][2], h2, aN0);
    aN1 = MFMA16(wA[5][2], h2, aN1);
    aN0 = MFMA16(wA[4][3], h3, aN0);
    aN1 = MFMA16(wA[5][3], h3, aN1);
    SFENCE();
    // ---- group 4: fused tail  h' = [e2n(Ez+h)+(h-Ez)] * rcp[(e2n+1)(1+Ez)] ----
    float a2v[8], gnv[8];
#pragma unroll
    for (int i = 0; i < 4; ++i) {
      a2v[i] = aN0[i]; a2v[4 + i] = aN1[i];
      gnv[i] = gu[4][i]; gnv[4 + i] = gu[5][i];
    }
    unsigned int rb_[8];
#pragma unroll
    for (int i = 0; i < 8; ++i) {
      float np  = __fmaf_rn(r[i], a2v[i], gnv[i]);
      float e2n = __builtin_amdgcn_exp2f(np);
      float num = __fmaf_rn(e2n, Ez[i] + h_old[i], h_old[i] - Ez[i]);
      float den = (e2n + 1.f) * (1.f + Ez[i]);
      float hn  = num * __builtin_amdgcn_rcpf(den);
      h_old[i] = hn;
      union { float ff; unsigned int u; } c; c.ff = hn;
      rb_[i] = c.u + 0x8000u;
    }
    unsigned int pk0 = __builtin_amdgcn_perm(rb_[1], rb_[0], 0x07060302u);
    unsigned int pk1 = __builtin_amdgcn_perm(rb_[3], rb_[2], 0x07060302u);
    unsigned int pk2 = __builtin_amdgcn_perm(rb_[5], rb_[4], 0x07060302u);
    unsigned int pk3 = __builtin_amdgcn_perm(rb_[7], rb_[6], 0x07060302u);
    *(ull*)(&hbuf[TO][m * SH + c0])      = ((ull)pk1 << 32) | pk0;
    *(ull*)(&hbuf[TO][m * SH + 64 + c0]) = ((ull)pk3 << 32) | pk2;
    __syncthreads();
  };

  for (int t = 0; t < T_; t += 2) {
    step(0, 1, t,     gA, gB);
    step(1, 0, t + 1, gB, gA);
  }

  // ---- epilogue: logits = hT @ W_fc^T + b_fc ----
#pragma unroll
  for (int i = 0; i < 4; ++i) {
    hf[m * H_ + c0 + i]      = h_old[i];
    hf[m * H_ + 64 + c0 + i] = h_old[4 + i];
  }
  __syncthreads();

  if (tid < 64) {
    int row = tid >> 2, vo = tid & 3;
    float s = b_fc[vo];
    const float* wv = W_fc + vo * H_;
    const float* hr = &hf[row * H_];
#pragma unroll 4
    for (int k = 0; k < H_; k += 4)
      s += hr[k] * wv[k] + hr[k + 1] * wv[k + 1]
         + hr[k + 2] * wv[k + 2] + hr[k + 3] * wv[k + 3];
    out[(g0 + row) * V_ + vo] = s;
  }
}

extern "C" void kernel_launch(void* const* d_in, const int* in_sizes, int n_in,
                              void* d_out, int out_size, void* d_ws, size_t ws_size,
                              hipStream_t stream) {
  const int*   x    = (const int*)d_in[0];
  const float* emb  = (const float*)d_in[1];
  const float* W_ih = (const float*)d_in[2];
  const float* W_hh = (const float*)d_in[3];
  const float* b_ih = (const float*)d_in[4];
  const float* b_hh = (const float*)d_in[5];
  const float* W_fc = (const float*)d_in[6];
  const float* b_fc = (const float*)d_in[7];
  float* out   = (float*)d_out;
  float* table = (float*)d_ws;     // 4*384 fp32 = 6 KB

  gi_table_kernel<<<(V_ * G3 + 255) / 256, 256, 0, stream>>>(emb, W_ih, b_ih, b_hh, table);
  gru_kernel<<<B_ / 16, 256, 0, stream>>>(x, W_hh, b_hh, W_fc, b_fc, table, out);
}